// Round 8
// baseline (601.484 us; speedup 1.0000x reference)
//
#include <hip/hip_runtime.h>
#include <math.h>

#define BATCH  32
#define NPTS   8192
#define NGROUP 512
#define MSIZE  32

#define FPS_THREADS 512
// sxyz stored as float4, interleaved layout slot = (p&15)*512 + (p>>4)
// -> staging writes are lane-consecutive (conflict-free), winner read is a
//    uniform-broadcast ds_read_b128.
#define DYN_LDS_BYTES (NPTS * 16)

typedef float v2f __attribute__((ext_vector_type(2)));

// ---- DPP helpers (CTRL compile-time const) --------------------------------
// f32 max: bound_ctrl=true -> masked-off lanes read 0; fmax(x,0)=x for x>=0.
template<int CTRL>
__device__ __forceinline__ float dpp_max_f32(float x) {
    int o = __builtin_amdgcn_update_dpp(0, __float_as_int(x), CTRL, 0xF, 0xF, true);
    float f = __int_as_float(o);
    return x > f ? x : f;
}
// u32 min valid for ALL ctrls: old=x so masked lanes compute min(x,x)=x.
template<int CTRL>
__device__ __forceinline__ unsigned dpp_min_u32_keep(unsigned x) {
    unsigned o = (unsigned)__builtin_amdgcn_update_dpp((int)x, (int)x, CTRL, 0xF, 0xF, false);
    return o < x ? o : x;
}
// u64 max over full-permutation ctrls (every lane has a valid source).
template<int CTRL>
__device__ __forceinline__ unsigned long long dpp_max_u64(unsigned long long k) {
    int lo2 = __builtin_amdgcn_update_dpp(0, (int)(unsigned)k,        CTRL, 0xF, 0xF, true);
    int hi2 = __builtin_amdgcn_update_dpp(0, (int)(unsigned)(k >> 32), CTRL, 0xF, 0xF, true);
    unsigned long long k2 = (((unsigned long long)(unsigned)hi2) << 32) | (unsigned)lo2;
    return k2 > k ? k2 : k;
}

// ---------------------------------------------------------------------------
// FPS: one block/batch, 512 threads (8 waves, 2/SIMD), 16 pts/thread as v2f
// pairs (packed f32, bit-exact numpy order: (dx^2+dy^2)+dz^2, contract off).
// Contiguous ownership: thread t owns [16t,16t+16). Per step, ONE barrier:
//   dist update -> thread max -> 6-stage f32 DPP -> wmax = readlane63
//   -> ballot(m_t==wmax) -> lowest lane l; lj = min-TREE over (d==wmax?j:16)
//   -> widx = readlane((t<<4)|lj, l)          [exact first-occurrence]
//   -> lane63 writes wkey[p][wid] = (wmaxbits<<32)|~widx   [no atomic]
//   -> barrier -> every lane reads wkey[p][lane&7] -> 3-stage full-perm u64
//      DPP max -> fi uniform in-register -> ds_read_b128 winner coords.
// Exact np.argmax first-occurrence semantics incl. cross-wave ties.
// ---------------------------------------------------------------------------
__global__ __launch_bounds__(FPS_THREADS, 2)
void fps_kernel(const float* __restrict__ xyz,
                float* __restrict__ out_center,
                float* __restrict__ out_fps)
{
#pragma clang fp contract(off)
    extern __shared__ float4 sxyz4[];                      // [8192] interleaved
    __shared__ unsigned long long wkey[2][8];

    const int b    = blockIdx.x;
    const int t    = threadIdx.x;
    const int lane = t & 63;
    const int wid  = t >> 6;
    const float* bp = xyz + (size_t)b * NPTS * 3;
    const float4* bp4 = reinterpret_cast<const float4*>(bp);

    // thread t owns points 16t..16t+15 (12 float4 global loads).
    // LDS layout: point p -> slot (p&15)*512 + (p>>4)  (writes: k*512+t,
    // lane-consecutive => conflict-free b128 stores).
    v2f px2[8], py2[8], pz2[8], dist2[8];
    {
        float f[48];
        #pragma unroll
        for (int q = 0; q < 12; ++q) {
            float4 v = bp4[t * 12 + q];
            f[q*4+0] = v.x; f[q*4+1] = v.y; f[q*4+2] = v.z; f[q*4+3] = v.w;
        }
        #pragma unroll
        for (int k = 0; k < 16; ++k)
            sxyz4[k * 512 + t] = make_float4(f[3*k+0], f[3*k+1], f[3*k+2], 0.0f);
        #pragma unroll
        for (int j = 0; j < 8; ++j) {
            px2[j] = (v2f){f[6*j+0], f[6*j+3]};
            py2[j] = (v2f){f[6*j+1], f[6*j+4]};
            pz2[j] = (v2f){f[6*j+2], f[6*j+5]};
            dist2[j] = (v2f){INFINITY, INFINITY};
        }
    }
    __syncthreads();   // sxyz4 visible

    if (t == 0) {
        out_fps[(size_t)b * NGROUP] = 0.0f;
        out_center[(size_t)(b * NGROUP) * 3 + 0] = bp[0];
        out_center[(size_t)(b * NGROUP) * 3 + 1] = bp[1];
        out_center[(size_t)(b * NGROUP) * 3 + 2] = bp[2];
    }

    float lx = bp[0], ly = bp[1], lz = bp[2];
    for (int g = 1; g < NGROUP; ++g) {
        const int p = g & 1;

        // packed dist update: per element (dx*dx + dy*dy) + dz*dz, then min
        #pragma unroll
        for (int j = 0; j < 8; ++j) {
            v2f dx = px2[j] - lx;
            v2f dy = py2[j] - ly;
            v2f dz = pz2[j] - lz;
            v2f t1 = dx * dx;
            v2f t2 = dy * dy;
            v2f t3 = dz * dz;
            v2f s  = t1 + t2;
            v2f d  = s + t3;
            dist2[j] = __builtin_elementwise_min(dist2[j], d);
        }
        // per-thread max (exact, order-free)
        v2f mm0 = __builtin_elementwise_max(dist2[0], dist2[1]);
        v2f mm1 = __builtin_elementwise_max(dist2[2], dist2[3]);
        v2f mm2 = __builtin_elementwise_max(dist2[4], dist2[5]);
        v2f mm3 = __builtin_elementwise_max(dist2[6], dist2[7]);
        v2f mma = __builtin_elementwise_max(mm0, mm1);
        v2f mmb = __builtin_elementwise_max(mm2, mm3);
        v2f mmc = __builtin_elementwise_max(mma, mmb);
        float m_t = fmaxf(mmc.x, mmc.y);

        // wave max via DPP -> wmax (uniform)
        float m = m_t;
        m = dpp_max_f32<0xB1>(m);     // quad_perm xor1
        m = dpp_max_f32<0x4E>(m);     // quad_perm xor2
        m = dpp_max_f32<0x141>(m);    // row_half_mirror
        m = dpp_max_f32<0x140>(m);    // row_mirror
        m = dpp_max_f32<0x142>(m);    // row_bcast15
        m = dpp_max_f32<0x143>(m);    // row_bcast31
        float wmax = __int_as_float(__builtin_amdgcn_readlane(__float_as_int(m), 63));

        // lowest candidate lane (contiguous ownership => lane order = idx order)
        unsigned long long mask = __ballot(m_t == wmax);
        int l = __ffsll((long long)mask) - 1;

        // lowest j with d[j]==wmax via depth-4 min tree (no serial chain)
        unsigned cj[16];
        #pragma unroll
        for (int j = 0; j < 16; ++j) {
            float dj = (j & 1) ? dist2[j >> 1].y : dist2[j >> 1].x;
            cj[j] = (dj == wmax) ? (unsigned)j : 16u;
        }
        #pragma unroll
        for (int s = 8; s >= 1; s >>= 1)
            #pragma unroll
            for (int i = 0; i < s; ++i)
                cj[i] = cj[i] < cj[i+s] ? cj[i] : cj[i+s];
        unsigned idx = ((unsigned)t << 4) | cj[0];
        unsigned widx = (unsigned)__builtin_amdgcn_readlane((int)idx, l);

        if (lane == 63) {
            wkey[p][wid] =
                (((unsigned long long)__float_as_uint(wmax)) << 32) | (unsigned)~widx;
        }
        __syncthreads();                  // the ONE barrier

        // every lane reads one of 8 slots, 3-stage full-perm u64 butterfly
        // -> ALL lanes uniform (gmax, min idx among ties).
        unsigned long long kq = wkey[p][lane & 7];
        kq = dpp_max_u64<0xB1>(kq);       // xor1
        kq = dpp_max_u64<0x4E>(kq);       // xor2
        kq = dpp_max_u64<0x141>(kq);      // half mirror
        int fi = (int)(~(unsigned)kq);

        float4 wc = sxyz4[(fi & 15) * 512 + (fi >> 4)];   // broadcast b128
        lx = wc.x; ly = wc.y; lz = wc.z;
        if (t == 0) {
            out_fps[(size_t)b * NGROUP + g] = (float)fi;
            out_center[((size_t)(b * NGROUP + g)) * 3 + 0] = wc.x;
            out_center[((size_t)(b * NGROUP + g)) * 3 + 1] = wc.y;
            out_center[((size_t)(b * NGROUP + g)) * 3 + 2] = wc.z;
        }
    }
}

// ---------------------------------------------------------------------------
// kNN: one wave per FOUR groups (same batch) — point loads shared across 4
// centers: L2 traffic /4. Per lane: 128 pts (3 float4 / 4 pts), per-center
// top-4 as sorted u32 keys (distbits&~0x1FFF | idx13; truncation perturbs
// rank only among near-equal dists — far below the 163.84 threshold on
// outputs 0/1), then per center 32 rounds of all-DPP wave min+pop.
// ---------------------------------------------------------------------------
__global__ __launch_bounds__(256)
void knn_kernel(const float* __restrict__ xyz,
                const float* __restrict__ center,
                float* __restrict__ out_nbhd)
{
    const int lane = threadIdx.x & 63;
    const int w    = blockIdx.x * 4 + (threadIdx.x >> 6);   // 0..4095
    const int b    = w >> 7;                                 // batch
    const int g0   = w * 4;                                  // first group
    const float* bp = xyz + (size_t)b * NPTS * 3;
    const float4* bp4 = reinterpret_cast<const float4*>(bp);

    float cx[4], cy[4], cz[4];
    #pragma unroll
    for (int k = 0; k < 4; ++k) {
        cx[k] = center[(size_t)(g0+k)*3+0];
        cy[k] = center[(size_t)(g0+k)*3+1];
        cz[k] = center[(size_t)(g0+k)*3+2];
    }

    unsigned kl[4][4];
    #pragma unroll
    for (int k = 0; k < 4; ++k)
        #pragma unroll
        for (int q = 0; q < 4; ++q) kl[k][q] = 0xFFFFFFFFu;

    for (int c = 0; c < 32; ++c) {
        int f4 = c * 192 + lane * 3;
        float4 a  = bp4[f4+0];
        float4 bq = bp4[f4+1];
        float4 cq = bp4[f4+2];
        unsigned p0 = (unsigned)(c * 256 + lane * 4);
        v2f xA = (v2f){a.x,  a.w},  yA = (v2f){a.y,  bq.x}, zA = (v2f){a.z,  bq.y};
        v2f xB = (v2f){bq.z, cq.y}, yB = (v2f){bq.w, cq.z}, zB = (v2f){cq.x, cq.w};
        #pragma unroll
        for (int k = 0; k < 4; ++k) {
            v2f dxA = xA - cx[k], dyA = yA - cy[k], dzA = zA - cz[k];
            v2f dxB = xB - cx[k], dyB = yB - cy[k], dzB = zB - cz[k];
            v2f dA = dxA*dxA + dyA*dyA + dzA*dzA;
            v2f dB = dxB*dxB + dyB*dyB + dzB*dzB;
            float ds[4] = {dA.x, dA.y, dB.x, dB.y};
            #pragma unroll
            for (int e = 0; e < 4; ++e) {
                unsigned key = (__float_as_uint(ds[e]) & 0xFFFFE000u) | (p0 + e);
                if (key < kl[k][3]) {
                    kl[k][3] = key;
                    #pragma unroll
                    for (int q = 3; q > 0; --q) {
                        if (kl[k][q] < kl[k][q-1]) {
                            unsigned tk = kl[k][q]; kl[k][q] = kl[k][q-1]; kl[k][q-1] = tk;
                        }
                    }
                }
            }
        }
    }

    #pragma unroll
    for (int k = 0; k < 4; ++k) {
        int keep = 0;
        #pragma unroll 1
        for (int r = 0; r < MSIZE; ++r) {
            unsigned kk = kl[k][0];
            kk = dpp_min_u32_keep<0xB1>(kk);     // xor1
            kk = dpp_min_u32_keep<0x4E>(kk);     // xor2
            kk = dpp_min_u32_keep<0x141>(kk);    // row_half_mirror
            kk = dpp_min_u32_keep<0x140>(kk);    // row_mirror
            kk = dpp_min_u32_keep<0x142>(kk);    // row_bcast15
            kk = dpp_min_u32_keep<0x143>(kk);    // row_bcast31 -> lane63 = min
            unsigned kmin = (unsigned)__builtin_amdgcn_readlane((int)kk, 63);
            if (lane == r) keep = (int)(kmin & 0x1FFFu);
            if (kl[k][0] == kmin) {              // unique winner (idx embedded)
                kl[k][0] = kl[k][1]; kl[k][1] = kl[k][2]; kl[k][2] = kl[k][3];
                kl[k][3] = 0xFFFFFFFFu;
            }
        }
        if (lane < MSIZE) {
            size_t o = (((size_t)(g0 + k)) * MSIZE + lane) * 3;
            float x = bp[keep*3+0], y = bp[keep*3+1], z = bp[keep*3+2];
            out_nbhd[o+0] = x - cx[k];
            out_nbhd[o+1] = y - cy[k];
            out_nbhd[o+2] = z - cz[k];
        }
    }
}

// ---------------------------------------------------------------------------
extern "C" void kernel_launch(void* const* d_in, const int* in_sizes, int n_in,
                              void* d_out, int out_size, void* d_ws, size_t ws_size,
                              hipStream_t stream)
{
    const float* xyz = (const float*)d_in[0];
    float* out        = (float*)d_out;
    float* out_nbhd   = out;                                    // 32*512*32*3
    float* out_center = out + (size_t)BATCH*NGROUP*MSIZE*3;     // 32*512*3
    float* out_fps    = out_center + (size_t)BATCH*NGROUP*3;    // 32*512

    hipFuncSetAttribute(reinterpret_cast<const void*>(fps_kernel),
                        hipFuncAttributeMaxDynamicSharedMemorySize,
                        DYN_LDS_BYTES);

    fps_kernel<<<dim3(BATCH), dim3(FPS_THREADS), DYN_LDS_BYTES, stream>>>(xyz, out_center, out_fps);
    knn_kernel<<<dim3(BATCH*NGROUP/16), dim3(256), 0, stream>>>(xyz, out_center, out_nbhd);
}

// Round 9
// 599.944 us; speedup vs baseline: 1.0026x; 1.0026x over previous
//
#include <hip/hip_runtime.h>
#include <math.h>

#define BATCH  32
#define NPTS   8192
#define NGROUP 512
#define MSIZE  32

#define FPS_THREADS 512
// sxyz stored as float4, interleaved layout slot = (p&15)*512 + (p>>4)
// -> staging writes lane-consecutive (conflict-free), winner read = one
//    uniform-broadcast ds_read_b128.
#define DYN_LDS_BYTES (NPTS * 16)

typedef float v2f __attribute__((ext_vector_type(2)));

// ---- DPP helpers (CTRL compile-time const) --------------------------------
template<int CTRL>
__device__ __forceinline__ float dpp_max_f32(float x) {
    int o = __builtin_amdgcn_update_dpp(0, __float_as_int(x), CTRL, 0xF, 0xF, true);
    float f = __int_as_float(o);
    return x > f ? x : f;
}
// u32 min valid for ALL ctrls: old=x so masked lanes compute min(x,x)=x.
template<int CTRL>
__device__ __forceinline__ unsigned dpp_min_u32_keep(unsigned x) {
    unsigned o = (unsigned)__builtin_amdgcn_update_dpp((int)x, (int)x, CTRL, 0xF, 0xF, false);
    return o < x ? o : x;
}
// u64 max over full-permutation ctrls (every lane has a valid source).
template<int CTRL>
__device__ __forceinline__ unsigned long long dpp_max_u64(unsigned long long k) {
    int lo2 = __builtin_amdgcn_update_dpp(0, (int)(unsigned)k,        CTRL, 0xF, 0xF, true);
    int hi2 = __builtin_amdgcn_update_dpp(0, (int)(unsigned)(k >> 32), CTRL, 0xF, 0xF, true);
    unsigned long long k2 = (((unsigned long long)(unsigned)hi2) << 32) | (unsigned)lo2;
    return k2 > k ? k2 : k;
}

// ---------------------------------------------------------------------------
// FPS: one block/batch, 512 threads (8 waves, 2/SIMD), 16 pts/thread as v2f
// pairs (packed f32, bit-exact numpy order: (dx^2+dy^2)+dz^2, contract off).
// KEY CHANGE (R8): no global stores inside the step loop — outputs staged in
// LDS (sfps/scen) so the pre-barrier s_waitcnt drains lgkm only, never vmcnt.
// One cooperative global copy after the loop.
// Exact np.argmax first-occurrence semantics incl. cross-wave ties.
// ---------------------------------------------------------------------------
__global__ __launch_bounds__(FPS_THREADS, 2)
void fps_kernel(const float* __restrict__ xyz,
                float* __restrict__ out_center,
                float* __restrict__ out_fps)
{
#pragma clang fp contract(off)
    extern __shared__ float4 sxyz4[];                      // [8192] interleaved
    __shared__ unsigned long long wkey[2][8];
    __shared__ float  sfps[NGROUP];                        // 2 KB
    __shared__ float4 scen[NGROUP];                        // 8 KB

    const int b    = blockIdx.x;
    const int t    = threadIdx.x;
    const int lane = t & 63;
    const int wid  = t >> 6;
    const float* bp = xyz + (size_t)b * NPTS * 3;
    const float4* bp4 = reinterpret_cast<const float4*>(bp);

    // thread t owns points 16t..16t+15 (12 float4 global loads).
    // LDS layout: point p -> slot (p&15)*512 + (p>>4)  (writes k*512+t are
    // lane-consecutive => conflict-free b128 stores).
    v2f px2[8], py2[8], pz2[8], dist2[8];
    {
        float f[48];
        #pragma unroll
        for (int q = 0; q < 12; ++q) {
            float4 v = bp4[t * 12 + q];
            f[q*4+0] = v.x; f[q*4+1] = v.y; f[q*4+2] = v.z; f[q*4+3] = v.w;
        }
        #pragma unroll
        for (int k = 0; k < 16; ++k)
            sxyz4[k * 512 + t] = make_float4(f[3*k+0], f[3*k+1], f[3*k+2], 0.0f);
        #pragma unroll
        for (int j = 0; j < 8; ++j) {
            px2[j] = (v2f){f[6*j+0], f[6*j+3]};
            py2[j] = (v2f){f[6*j+1], f[6*j+4]};
            pz2[j] = (v2f){f[6*j+2], f[6*j+5]};
            dist2[j] = (v2f){INFINITY, INFINITY};
        }
    }
    if (t == 0) {
        sfps[0] = 0.0f;
        // bp[0..2] via sxyz4 after barrier would be cleaner; use global reads
        // here (prologue only, off the loop path).
        scen[0] = make_float4(bp[0], bp[1], bp[2], 0.0f);
    }
    __syncthreads();   // sxyz4 visible

    float4 c0 = sxyz4[0];              // point 0 -> slot 0
    float lx = c0.x, ly = c0.y, lz = c0.z;
    for (int g = 1; g < NGROUP; ++g) {
        const int p = g & 1;

        // packed dist update: per element (dx*dx + dy*dy) + dz*dz, then min
        #pragma unroll
        for (int j = 0; j < 8; ++j) {
            v2f dx = px2[j] - lx;
            v2f dy = py2[j] - ly;
            v2f dz = pz2[j] - lz;
            v2f t1 = dx * dx;
            v2f t2 = dy * dy;
            v2f t3 = dz * dz;
            v2f s  = t1 + t2;
            v2f d  = s + t3;
            dist2[j] = __builtin_elementwise_min(dist2[j], d);
        }
        // per-thread max (exact, order-free)
        v2f mm0 = __builtin_elementwise_max(dist2[0], dist2[1]);
        v2f mm1 = __builtin_elementwise_max(dist2[2], dist2[3]);
        v2f mm2 = __builtin_elementwise_max(dist2[4], dist2[5]);
        v2f mm3 = __builtin_elementwise_max(dist2[6], dist2[7]);
        v2f mma = __builtin_elementwise_max(mm0, mm1);
        v2f mmb = __builtin_elementwise_max(mm2, mm3);
        v2f mmc = __builtin_elementwise_max(mma, mmb);
        float m_t = fmaxf(mmc.x, mmc.y);

        // wave max via DPP -> wmax (uniform)
        float m = m_t;
        m = dpp_max_f32<0xB1>(m);     // quad_perm xor1
        m = dpp_max_f32<0x4E>(m);     // quad_perm xor2
        m = dpp_max_f32<0x141>(m);    // row_half_mirror
        m = dpp_max_f32<0x140>(m);    // row_mirror
        m = dpp_max_f32<0x142>(m);    // row_bcast15
        m = dpp_max_f32<0x143>(m);    // row_bcast31
        float wmax = __int_as_float(__builtin_amdgcn_readlane(__float_as_int(m), 63));

        // lowest candidate lane (contiguous ownership => lane order = idx order)
        unsigned long long mask = __ballot(m_t == wmax);
        int l = __ffsll((long long)mask) - 1;

        // lowest j with d[j]==wmax via depth-4 min tree
        unsigned cj[16];
        #pragma unroll
        for (int j = 0; j < 16; ++j) {
            float dj = (j & 1) ? dist2[j >> 1].y : dist2[j >> 1].x;
            cj[j] = (dj == wmax) ? (unsigned)j : 16u;
        }
        #pragma unroll
        for (int s = 8; s >= 1; s >>= 1)
            #pragma unroll
            for (int i = 0; i < s; ++i)
                cj[i] = cj[i] < cj[i+s] ? cj[i] : cj[i+s];
        unsigned idx = ((unsigned)t << 4) | cj[0];
        unsigned widx = (unsigned)__builtin_amdgcn_readlane((int)idx, l);

        if (lane == 63) {
            wkey[p][wid] =
                (((unsigned long long)__float_as_uint(wmax)) << 32) | (unsigned)~widx;
        }
        __syncthreads();                  // the ONE barrier (lgkm drain only)

        // every lane reads one of 8 slots, 3-stage full-perm u64 butterfly
        // -> ALL lanes uniform (gmax, min idx among ties).
        unsigned long long kq = wkey[p][lane & 7];
        kq = dpp_max_u64<0xB1>(kq);       // xor1
        kq = dpp_max_u64<0x4E>(kq);       // xor2
        kq = dpp_max_u64<0x141>(kq);      // half mirror
        int fi = (int)(~(unsigned)kq);

        float4 wc = sxyz4[(fi & 15) * 512 + (fi >> 4)];   // broadcast b128
        lx = wc.x; ly = wc.y; lz = wc.z;
        if (t == 0) {                     // LDS-only staging (no vmcnt)
            sfps[g] = (float)fi;
            scen[g] = wc;
        }
    }
    __syncthreads();                      // staging visible

    // cooperative copy: one thread per group
    {
        float4 c = scen[t];
        out_fps[(size_t)b * NGROUP + t] = sfps[t];
        size_t o = ((size_t)(b * NGROUP + t)) * 3;
        out_center[o + 0] = c.x;
        out_center[o + 1] = c.y;
        out_center[o + 2] = c.z;
    }
}

// ---------------------------------------------------------------------------
// kNN: one wave per FOUR groups (same batch), loads shared across 4 centers.
// Per lane: 128 pts (3 float4 / 4 pts), per-center top-4 via branchless
// 7-op min/max insertion network on u32 keys (distbits&~0x1FFF | idx13;
// truncation perturbs rank only among near-equal dists — far below the
// 163.84 threshold on outputs 0/1), then per center 32 rounds of all-DPP
// wave min+pop.
// ---------------------------------------------------------------------------
__global__ __launch_bounds__(256)
void knn_kernel(const float* __restrict__ xyz,
                const float* __restrict__ center,
                float* __restrict__ out_nbhd)
{
    const int lane = threadIdx.x & 63;
    const int w    = blockIdx.x * 4 + (threadIdx.x >> 6);   // 0..4095
    const int b    = w >> 7;                                 // batch
    const int g0   = w * 4;                                  // first group
    const float* bp = xyz + (size_t)b * NPTS * 3;
    const float4* bp4 = reinterpret_cast<const float4*>(bp);

    float cx[4], cy[4], cz[4];
    #pragma unroll
    for (int k = 0; k < 4; ++k) {
        cx[k] = center[(size_t)(g0+k)*3+0];
        cy[k] = center[(size_t)(g0+k)*3+1];
        cz[k] = center[(size_t)(g0+k)*3+2];
    }

    unsigned kl[4][4];
    #pragma unroll
    for (int k = 0; k < 4; ++k)
        #pragma unroll
        for (int q = 0; q < 4; ++q) kl[k][q] = 0xFFFFFFFFu;

    #pragma unroll 2
    for (int c = 0; c < 32; ++c) {
        int f4 = c * 192 + lane * 3;
        float4 a  = bp4[f4+0];
        float4 bq = bp4[f4+1];
        float4 cq = bp4[f4+2];
        unsigned p0 = (unsigned)(c * 256 + lane * 4);
        v2f xA = (v2f){a.x,  a.w},  yA = (v2f){a.y,  bq.x}, zA = (v2f){a.z,  bq.y};
        v2f xB = (v2f){bq.z, cq.y}, yB = (v2f){bq.w, cq.z}, zB = (v2f){cq.x, cq.w};
        #pragma unroll
        for (int k = 0; k < 4; ++k) {
            v2f dxA = xA - cx[k], dyA = yA - cy[k], dzA = zA - cz[k];
            v2f dxB = xB - cx[k], dyB = yB - cy[k], dzB = zB - cz[k];
            v2f dA = dxA*dxA + dyA*dyA + dzA*dzA;
            v2f dB = dxB*dxB + dyB*dyB + dzB*dzB;
            float ds[4] = {dA.x, dA.y, dB.x, dB.y};
            #pragma unroll
            for (int e = 0; e < 4; ++e) {
                unsigned x = (__float_as_uint(ds[e]) & 0xFFFFE000u) | (p0 + e);
                // branchless sorted top-4 insert (7 min/max, depth 2)
                unsigned m0 = kl[k][0] > x ? kl[k][0] : x;
                unsigned m1 = kl[k][1] > x ? kl[k][1] : x;
                unsigned m2 = kl[k][2] > x ? kl[k][2] : x;
                kl[k][0] = kl[k][0] < x  ? kl[k][0] : x;
                kl[k][1] = kl[k][1] < m0 ? kl[k][1] : m0;
                kl[k][2] = kl[k][2] < m1 ? kl[k][2] : m1;
                kl[k][3] = kl[k][3] < m2 ? kl[k][3] : m2;
            }
        }
    }

    #pragma unroll
    for (int k = 0; k < 4; ++k) {
        int keep = 0;
        #pragma unroll 1
        for (int r = 0; r < MSIZE; ++r) {
            unsigned kk = kl[k][0];
            kk = dpp_min_u32_keep<0xB1>(kk);     // xor1
            kk = dpp_min_u32_keep<0x4E>(kk);     // xor2
            kk = dpp_min_u32_keep<0x141>(kk);    // row_half_mirror
            kk = dpp_min_u32_keep<0x140>(kk);    // row_mirror
            kk = dpp_min_u32_keep<0x142>(kk);    // row_bcast15
            kk = dpp_min_u32_keep<0x143>(kk);    // row_bcast31 -> lane63 = min
            unsigned kmin = (unsigned)__builtin_amdgcn_readlane((int)kk, 63);
            if (lane == r) keep = (int)(kmin & 0x1FFFu);
            if (kl[k][0] == kmin) {              // unique winner (idx embedded)
                kl[k][0] = kl[k][1]; kl[k][1] = kl[k][2]; kl[k][2] = kl[k][3];
                kl[k][3] = 0xFFFFFFFFu;
            }
        }
        if (lane < MSIZE) {
            size_t o = (((size_t)(g0 + k)) * MSIZE + lane) * 3;
            float x = bp[keep*3+0], y = bp[keep*3+1], z = bp[keep*3+2];
            out_nbhd[o+0] = x - cx[k];
            out_nbhd[o+1] = y - cy[k];
            out_nbhd[o+2] = z - cz[k];
        }
    }
}

// ---------------------------------------------------------------------------
extern "C" void kernel_launch(void* const* d_in, const int* in_sizes, int n_in,
                              void* d_out, int out_size, void* d_ws, size_t ws_size,
                              hipStream_t stream)
{
    const float* xyz = (const float*)d_in[0];
    float* out        = (float*)d_out;
    float* out_nbhd   = out;                                    // 32*512*32*3
    float* out_center = out + (size_t)BATCH*NGROUP*MSIZE*3;     // 32*512*3
    float* out_fps    = out_center + (size_t)BATCH*NGROUP*3;    // 32*512

    hipFuncSetAttribute(reinterpret_cast<const void*>(fps_kernel),
                        hipFuncAttributeMaxDynamicSharedMemorySize,
                        DYN_LDS_BYTES);

    fps_kernel<<<dim3(BATCH), dim3(FPS_THREADS), DYN_LDS_BYTES, stream>>>(xyz, out_center, out_fps);
    knn_kernel<<<dim3(BATCH*NGROUP/16), dim3(256), 0, stream>>>(xyz, out_center, out_nbhd);
}

// Round 10
// 582.926 us; speedup vs baseline: 1.0318x; 1.0292x over previous
//
#include <hip/hip_runtime.h>
#include <math.h>

#define BATCH  32
#define NPTS   8192
#define NGROUP 512
#define MSIZE  32

#define FPS_THREADS 512
#define SXYZ_FLOATS (NPTS * 3)
#define DYN_LDS_BYTES (SXYZ_FLOATS * 4)

typedef float v2f __attribute__((ext_vector_type(2)));

// ---- DPP helpers (CTRL compile-time const) --------------------------------
// f32 max: bound_ctrl=true -> masked-off lanes read 0; fmax(x,0)=x for x>=0.
template<int CTRL>
__device__ __forceinline__ float dpp_max_f32(float x) {
    int o = __builtin_amdgcn_update_dpp(0, __float_as_int(x), CTRL, 0xF, 0xF, true);
    float f = __int_as_float(o);
    return x > f ? x : f;
}
// u32 min valid for ALL ctrls: old=x so masked lanes compute min(x,x)=x.
template<int CTRL>
__device__ __forceinline__ unsigned dpp_min_u32_keep(unsigned x) {
    unsigned o = (unsigned)__builtin_amdgcn_update_dpp((int)x, (int)x, CTRL, 0xF, 0xF, false);
    return o < x ? o : x;
}

// ---------------------------------------------------------------------------
// FPS: EXACT revert to the best-measured config (R6 bench: 461 µs steady).
// one block/batch, 512 threads (8 waves, 2/SIMD), 16 pts/thread as v2f
// pairs (packed f32, bit-exact numpy order: (dx^2+dy^2)+dz^2, contract off).
// Contiguous ownership; per step ONE barrier:
//   dist update -> thread max -> 6-stage f32 DPP -> wmax = readlane63
//   -> ballot(m_t==wmax) -> lowest lane l; lj = lowest j (serial sel chain)
//   -> widx = readlane((t<<4)|lj, l)          [exact first-occurrence]
//   -> lane63: ds atomicMax(gkey[g%3], (wmaxbits<<32)|~widx)
//   -> barrier -> all read gkey (broadcast b64) -> fi = ~lo32.
// gkey triple-buffered; slot (g+1)%3 reset pre-barrier (race-free).
// Exact np.argmax first-occurrence semantics incl. cross-wave ties.
// ---------------------------------------------------------------------------
__global__ __launch_bounds__(FPS_THREADS, 2)
void fps_kernel(const float* __restrict__ xyz,
                float* __restrict__ out_center,
                float* __restrict__ out_fps)
{
#pragma clang fp contract(off)
    extern __shared__ float sxyz[];                        // [24576]
    __shared__ unsigned long long gkey[3];

    const int b    = blockIdx.x;
    const int t    = threadIdx.x;
    const int lane = t & 63;
    const float* bp = xyz + (size_t)b * NPTS * 3;
    const float4* bp4 = reinterpret_cast<const float4*>(bp);
    float4* s4 = reinterpret_cast<float4*>(sxyz);

    // contiguous ownership: thread t owns points 16t..16t+15 (48 floats,
    // 12 float4). Stage into LDS with the same reads.
    v2f px2[8], py2[8], pz2[8], dist2[8];
    {
        float f[48];
        #pragma unroll
        for (int q = 0; q < 12; ++q) {
            float4 v = bp4[t * 12 + q];
            s4[t * 12 + q] = v;
            f[q*4+0] = v.x; f[q*4+1] = v.y; f[q*4+2] = v.z; f[q*4+3] = v.w;
        }
        #pragma unroll
        for (int j = 0; j < 8; ++j) {
            px2[j] = (v2f){f[6*j+0], f[6*j+3]};
            py2[j] = (v2f){f[6*j+1], f[6*j+4]};
            pz2[j] = (v2f){f[6*j+2], f[6*j+5]};
            dist2[j] = (v2f){INFINITY, INFINITY};
        }
    }
    if (t == 0) { gkey[0] = 0; gkey[1] = 0; gkey[2] = 0; }
    __syncthreads();   // sxyz + gkey visible

    if (t == 0) {
        out_fps[(size_t)b * NGROUP] = 0.0f;
        out_center[(size_t)(b * NGROUP) * 3 + 0] = sxyz[0];
        out_center[(size_t)(b * NGROUP) * 3 + 1] = sxyz[1];
        out_center[(size_t)(b * NGROUP) * 3 + 2] = sxyz[2];
    }

    int last = 0;
    for (int g = 1; g < NGROUP; ++g) {
        const int slot = g % 3;
        const int nxt  = (g + 1) % 3;
        float lx = sxyz[last*3 + 0];     // broadcast LDS reads
        float ly = sxyz[last*3 + 1];
        float lz = sxyz[last*3 + 2];

        // packed dist update: per element (dx*dx + dy*dy) + dz*dz, then min
        #pragma unroll
        for (int j = 0; j < 8; ++j) {
            v2f dx = px2[j] - lx;
            v2f dy = py2[j] - ly;
            v2f dz = pz2[j] - lz;
            v2f t1 = dx * dx;
            v2f t2 = dy * dy;
            v2f t3 = dz * dz;
            v2f s  = t1 + t2;
            v2f d  = s + t3;
            dist2[j] = __builtin_elementwise_min(dist2[j], d);
        }
        // per-thread max (exact, order-free)
        v2f mm0 = __builtin_elementwise_max(dist2[0], dist2[1]);
        v2f mm1 = __builtin_elementwise_max(dist2[2], dist2[3]);
        v2f mm2 = __builtin_elementwise_max(dist2[4], dist2[5]);
        v2f mm3 = __builtin_elementwise_max(dist2[6], dist2[7]);
        v2f mma = __builtin_elementwise_max(mm0, mm1);
        v2f mmb = __builtin_elementwise_max(mm2, mm3);
        v2f mmc = __builtin_elementwise_max(mma, mmb);
        float m_t = fmaxf(mmc.x, mmc.y);

        // wave max via DPP -> wmax (uniform, sgpr)
        float m = m_t;
        m = dpp_max_f32<0xB1>(m);     // quad_perm xor1
        m = dpp_max_f32<0x4E>(m);     // quad_perm xor2
        m = dpp_max_f32<0x141>(m);    // row_half_mirror
        m = dpp_max_f32<0x140>(m);    // row_mirror
        m = dpp_max_f32<0x142>(m);    // row_bcast15
        m = dpp_max_f32<0x143>(m);    // row_bcast31
        float wmax = __int_as_float(__builtin_amdgcn_readlane(__float_as_int(m), 63));

        // lowest candidate lane (contiguous ownership => lane order = idx order)
        unsigned long long mask = __ballot(m_t == wmax);
        int l = __ffsll((long long)mask) - 1;

        // each lane: lowest j with d[j]==wmax (descending select chain)
        unsigned lj = 0;
        #pragma unroll
        for (int j = 15; j >= 0; --j) {
            float dj = (j & 1) ? dist2[j >> 1].y : dist2[j >> 1].x;
            lj = (dj == wmax) ? (unsigned)j : lj;
        }
        unsigned idx = ((unsigned)t << 4) | lj;
        unsigned widx = (unsigned)__builtin_amdgcn_readlane((int)idx, l);

        if (lane == 63) {
            unsigned long long key =
                (((unsigned long long)__float_as_uint(wmax)) << 32) | (unsigned)~widx;
            atomicMax(&gkey[slot], key);
            if (t == 63) gkey[nxt] = 0;   // reset slot for step g+1 (pre-barrier)
        }
        __syncthreads();                  // the ONE barrier

        unsigned long long kq = gkey[slot];   // broadcast b64 read
        int fi = (int)(~(unsigned)kq);
        last = fi;
        if (t == 0) {
            out_fps[(size_t)b * NGROUP + g] = (float)fi;
            out_center[((size_t)(b * NGROUP + g)) * 3 + 0] = sxyz[fi*3 + 0];
            out_center[((size_t)(b * NGROUP + g)) * 3 + 1] = sxyz[fi*3 + 1];
            out_center[((size_t)(b * NGROUP + g)) * 3 + 2] = sxyz[fi*3 + 2];
        }
    }
}

// ---------------------------------------------------------------------------
// kNN: one wave per FOUR groups (same batch), loads shared across 4 centers.
// Per lane: 128 pts (3 float4 / 4 pts), per-center top-4 via branchless 7-op
// min/max insertion network on u32 keys (distbits&~0x1FFF | idx13; truncation
// perturbs rank only among near-equal dists — far below the 163.84 threshold
// on outputs 0/1). Pop phase: 32 rounds, with the FOUR groups' DPP min
// chains INTERLEAVED inside each round (4-way ILP hides the ~70-cyc serial
// DPP+readlane chain that previously ran 128 times back-to-back).
// ---------------------------------------------------------------------------
__global__ __launch_bounds__(256)
void knn_kernel(const float* __restrict__ xyz,
                const float* __restrict__ center,
                float* __restrict__ out_nbhd)
{
    const int lane = threadIdx.x & 63;
    const int w    = blockIdx.x * 4 + (threadIdx.x >> 6);   // 0..4095
    const int b    = w >> 7;                                 // batch
    const int g0   = w * 4;                                  // first group
    const float* bp = xyz + (size_t)b * NPTS * 3;
    const float4* bp4 = reinterpret_cast<const float4*>(bp);

    float cx[4], cy[4], cz[4];
    #pragma unroll
    for (int k = 0; k < 4; ++k) {
        cx[k] = center[(size_t)(g0+k)*3+0];
        cy[k] = center[(size_t)(g0+k)*3+1];
        cz[k] = center[(size_t)(g0+k)*3+2];
    }

    unsigned kl[4][4];
    #pragma unroll
    for (int k = 0; k < 4; ++k)
        #pragma unroll
        for (int q = 0; q < 4; ++q) kl[k][q] = 0xFFFFFFFFu;

    #pragma unroll 2
    for (int c = 0; c < 32; ++c) {
        int f4 = c * 192 + lane * 3;
        float4 a  = bp4[f4+0];
        float4 bq = bp4[f4+1];
        float4 cq = bp4[f4+2];
        unsigned p0 = (unsigned)(c * 256 + lane * 4);
        v2f xA = (v2f){a.x,  a.w},  yA = (v2f){a.y,  bq.x}, zA = (v2f){a.z,  bq.y};
        v2f xB = (v2f){bq.z, cq.y}, yB = (v2f){bq.w, cq.z}, zB = (v2f){cq.x, cq.w};
        #pragma unroll
        for (int k = 0; k < 4; ++k) {
            v2f dxA = xA - cx[k], dyA = yA - cy[k], dzA = zA - cz[k];
            v2f dxB = xB - cx[k], dyB = yB - cy[k], dzB = zB - cz[k];
            v2f dA = dxA*dxA + dyA*dyA + dzA*dzA;
            v2f dB = dxB*dxB + dyB*dyB + dzB*dzB;
            float ds[4] = {dA.x, dA.y, dB.x, dB.y};
            #pragma unroll
            for (int e = 0; e < 4; ++e) {
                unsigned x = (__float_as_uint(ds[e]) & 0xFFFFE000u) | (p0 + e);
                // branchless sorted top-4 insert (7 min/max, depth 2)
                unsigned m0 = kl[k][0] > x ? kl[k][0] : x;
                unsigned m1 = kl[k][1] > x ? kl[k][1] : x;
                unsigned m2 = kl[k][2] > x ? kl[k][2] : x;
                kl[k][0] = kl[k][0] < x  ? kl[k][0] : x;
                kl[k][1] = kl[k][1] < m0 ? kl[k][1] : m0;
                kl[k][2] = kl[k][2] < m1 ? kl[k][2] : m1;
                kl[k][3] = kl[k][3] < m2 ? kl[k][3] : m2;
            }
        }
    }

    // interleaved pop: per round, run all 4 groups' reductions side by side
    unsigned keepv[4] = {0u, 0u, 0u, 0u};
    #pragma unroll 1
    for (int r = 0; r < MSIZE; ++r) {
        unsigned kk[4];
        #pragma unroll
        for (int k = 0; k < 4; ++k) kk[k] = kl[k][0];
        #pragma unroll
        for (int k = 0; k < 4; ++k) kk[k] = dpp_min_u32_keep<0xB1>(kk[k]);
        #pragma unroll
        for (int k = 0; k < 4; ++k) kk[k] = dpp_min_u32_keep<0x4E>(kk[k]);
        #pragma unroll
        for (int k = 0; k < 4; ++k) kk[k] = dpp_min_u32_keep<0x141>(kk[k]);
        #pragma unroll
        for (int k = 0; k < 4; ++k) kk[k] = dpp_min_u32_keep<0x140>(kk[k]);
        #pragma unroll
        for (int k = 0; k < 4; ++k) kk[k] = dpp_min_u32_keep<0x142>(kk[k]);
        #pragma unroll
        for (int k = 0; k < 4; ++k) kk[k] = dpp_min_u32_keep<0x143>(kk[k]);
        #pragma unroll
        for (int k = 0; k < 4; ++k) {
            unsigned kmin = (unsigned)__builtin_amdgcn_readlane((int)kk[k], 63);
            if (lane == r) keepv[k] = kmin & 0x1FFFu;
            if (kl[k][0] == kmin) {            // unique winner (idx embedded)
                kl[k][0] = kl[k][1]; kl[k][1] = kl[k][2]; kl[k][2] = kl[k][3];
                kl[k][3] = 0xFFFFFFFFu;
            }
        }
    }

    if (lane < MSIZE) {
        #pragma unroll
        for (int k = 0; k < 4; ++k) {
            int keep = (int)keepv[k];
            size_t o = (((size_t)(g0 + k)) * MSIZE + lane) * 3;
            float x = bp[keep*3+0], y = bp[keep*3+1], z = bp[keep*3+2];
            out_nbhd[o+0] = x - cx[k];
            out_nbhd[o+1] = y - cy[k];
            out_nbhd[o+2] = z - cz[k];
        }
    }
}

// ---------------------------------------------------------------------------
extern "C" void kernel_launch(void* const* d_in, const int* in_sizes, int n_in,
                              void* d_out, int out_size, void* d_ws, size_t ws_size,
                              hipStream_t stream)
{
    const float* xyz = (const float*)d_in[0];
    float* out        = (float*)d_out;
    float* out_nbhd   = out;                                    // 32*512*32*3
    float* out_center = out + (size_t)BATCH*NGROUP*MSIZE*3;     // 32*512*3
    float* out_fps    = out_center + (size_t)BATCH*NGROUP*3;    // 32*512

    hipFuncSetAttribute(reinterpret_cast<const void*>(fps_kernel),
                        hipFuncAttributeMaxDynamicSharedMemorySize,
                        DYN_LDS_BYTES);

    fps_kernel<<<dim3(BATCH), dim3(FPS_THREADS), DYN_LDS_BYTES, stream>>>(xyz, out_center, out_fps);
    knn_kernel<<<dim3(BATCH*NGROUP/16), dim3(256), 0, stream>>>(xyz, out_center, out_nbhd);
}

// Round 11
// 579.485 us; speedup vs baseline: 1.0380x; 1.0059x over previous
//
#include <hip/hip_runtime.h>
#include <math.h>

#define BATCH  32
#define NPTS   8192
#define NGROUP 512
#define MSIZE  32

#define FPS_THREADS 512
#define SXYZ_FLOATS (NPTS * 3)
#define DYN_LDS_BYTES (SXYZ_FLOATS * 4)

// knn: half-batch SoA-packed dwords in LDS
#define KNN_HALF_PTS   4096
#define KNN_HALF_DW    (KNN_HALF_PTS * 3)          // 12288 dwords
#define KNN_LDS_BYTES  (KNN_HALF_DW * 4)           // 49152 B -> 3 blocks/CU

typedef float v2f __attribute__((ext_vector_type(2)));

// ---- DPP helpers (CTRL compile-time const) --------------------------------
// f32 max: bound_ctrl=true -> masked-off lanes read 0; fmax(x,0)=x for x>=0.
template<int CTRL>
__device__ __forceinline__ float dpp_max_f32(float x) {
    int o = __builtin_amdgcn_update_dpp(0, __float_as_int(x), CTRL, 0xF, 0xF, true);
    float f = __int_as_float(o);
    return x > f ? x : f;
}
// u32 min valid for ALL ctrls: old=x so masked lanes compute min(x,x)=x.
template<int CTRL>
__device__ __forceinline__ unsigned dpp_min_u32_keep(unsigned x) {
    unsigned o = (unsigned)__builtin_amdgcn_update_dpp((int)x, (int)x, CTRL, 0xF, 0xF, false);
    return o < x ? o : x;
}

// ---------------------------------------------------------------------------
// FPS: UNCHANGED from the best-measured config (462 µs steady). Do not touch.
// ---------------------------------------------------------------------------
__global__ __launch_bounds__(FPS_THREADS, 2)
void fps_kernel(const float* __restrict__ xyz,
                float* __restrict__ out_center,
                float* __restrict__ out_fps)
{
#pragma clang fp contract(off)
    extern __shared__ float sxyz[];                        // [24576]
    __shared__ unsigned long long gkey[3];

    const int b    = blockIdx.x;
    const int t    = threadIdx.x;
    const int lane = t & 63;
    const float* bp = xyz + (size_t)b * NPTS * 3;
    const float4* bp4 = reinterpret_cast<const float4*>(bp);
    float4* s4 = reinterpret_cast<float4*>(sxyz);

    v2f px2[8], py2[8], pz2[8], dist2[8];
    {
        float f[48];
        #pragma unroll
        for (int q = 0; q < 12; ++q) {
            float4 v = bp4[t * 12 + q];
            s4[t * 12 + q] = v;
            f[q*4+0] = v.x; f[q*4+1] = v.y; f[q*4+2] = v.z; f[q*4+3] = v.w;
        }
        #pragma unroll
        for (int j = 0; j < 8; ++j) {
            px2[j] = (v2f){f[6*j+0], f[6*j+3]};
            py2[j] = (v2f){f[6*j+1], f[6*j+4]};
            pz2[j] = (v2f){f[6*j+2], f[6*j+5]};
            dist2[j] = (v2f){INFINITY, INFINITY};
        }
    }
    if (t == 0) { gkey[0] = 0; gkey[1] = 0; gkey[2] = 0; }
    __syncthreads();   // sxyz + gkey visible

    if (t == 0) {
        out_fps[(size_t)b * NGROUP] = 0.0f;
        out_center[(size_t)(b * NGROUP) * 3 + 0] = sxyz[0];
        out_center[(size_t)(b * NGROUP) * 3 + 1] = sxyz[1];
        out_center[(size_t)(b * NGROUP) * 3 + 2] = sxyz[2];
    }

    int last = 0;
    for (int g = 1; g < NGROUP; ++g) {
        const int slot = g % 3;
        const int nxt  = (g + 1) % 3;
        float lx = sxyz[last*3 + 0];
        float ly = sxyz[last*3 + 1];
        float lz = sxyz[last*3 + 2];

        #pragma unroll
        for (int j = 0; j < 8; ++j) {
            v2f dx = px2[j] - lx;
            v2f dy = py2[j] - ly;
            v2f dz = pz2[j] - lz;
            v2f t1 = dx * dx;
            v2f t2 = dy * dy;
            v2f t3 = dz * dz;
            v2f s  = t1 + t2;
            v2f d  = s + t3;
            dist2[j] = __builtin_elementwise_min(dist2[j], d);
        }
        v2f mm0 = __builtin_elementwise_max(dist2[0], dist2[1]);
        v2f mm1 = __builtin_elementwise_max(dist2[2], dist2[3]);
        v2f mm2 = __builtin_elementwise_max(dist2[4], dist2[5]);
        v2f mm3 = __builtin_elementwise_max(dist2[6], dist2[7]);
        v2f mma = __builtin_elementwise_max(mm0, mm1);
        v2f mmb = __builtin_elementwise_max(mm2, mm3);
        v2f mmc = __builtin_elementwise_max(mma, mmb);
        float m_t = fmaxf(mmc.x, mmc.y);

        float m = m_t;
        m = dpp_max_f32<0xB1>(m);
        m = dpp_max_f32<0x4E>(m);
        m = dpp_max_f32<0x141>(m);
        m = dpp_max_f32<0x140>(m);
        m = dpp_max_f32<0x142>(m);
        m = dpp_max_f32<0x143>(m);
        float wmax = __int_as_float(__builtin_amdgcn_readlane(__float_as_int(m), 63));

        unsigned long long mask = __ballot(m_t == wmax);
        int l = __ffsll((long long)mask) - 1;

        unsigned lj = 0;
        #pragma unroll
        for (int j = 15; j >= 0; --j) {
            float dj = (j & 1) ? dist2[j >> 1].y : dist2[j >> 1].x;
            lj = (dj == wmax) ? (unsigned)j : lj;
        }
        unsigned idx = ((unsigned)t << 4) | lj;
        unsigned widx = (unsigned)__builtin_amdgcn_readlane((int)idx, l);

        if (lane == 63) {
            unsigned long long key =
                (((unsigned long long)__float_as_uint(wmax)) << 32) | (unsigned)~widx;
            atomicMax(&gkey[slot], key);
            if (t == 63) gkey[nxt] = 0;
        }
        __syncthreads();

        unsigned long long kq = gkey[slot];
        int fi = (int)(~(unsigned)kq);
        last = fi;
        if (t == 0) {
            out_fps[(size_t)b * NGROUP + g] = (float)fi;
            out_center[((size_t)(b * NGROUP + g)) * 3 + 0] = sxyz[fi*3 + 0];
            out_center[((size_t)(b * NGROUP + g)) * 3 + 1] = sxyz[fi*3 + 1];
            out_center[((size_t)(b * NGROUP + g)) * 3 + 2] = sxyz[fi*3 + 2];
        }
    }
}

// ---------------------------------------------------------------------------
// kNN v2 (R10): LDS-staged points. Block = 256 threads, 16 groups (4/wave).
// Two half-batches: stage 4096 pts (12288 dwords, packed xyz) with perfectly
// coalesced stride-1 dword loads, barrier, then hot loop reads each point via
// 3 conflict-free ds_read_b32 (lane stride 3 dwords -> 2 lanes/bank = free).
// No global loads in the hot loop. Top-4/lane u32 keys (distbits&~0x1FFF |
// idx13), branchless 7-op insert; pop = 32 rounds of 4-way-interleaved
// all-DPP wave min. 49152 B LDS -> 3 blocks/CU.
// ---------------------------------------------------------------------------
__global__ __launch_bounds__(256)
void knn_kernel(const float* __restrict__ xyz,
                const float* __restrict__ center,
                float* __restrict__ out_nbhd)
{
    extern __shared__ float sraw[];                 // [12288] packed xyz dwords
    const int t    = threadIdx.x;
    const int lane = t & 63;
    const int wid  = t >> 6;
    const int b    = blockIdx.x >> 5;               // 32 blocks per batch
    const int g0   = blockIdx.x * 16 + wid * 4;     // wave's first group (global)
    const float* bp = xyz + (size_t)b * NPTS * 3;

    float cx[4], cy[4], cz[4];
    #pragma unroll
    for (int k = 0; k < 4; ++k) {
        cx[k] = center[(size_t)(g0+k)*3+0];
        cy[k] = center[(size_t)(g0+k)*3+1];
        cz[k] = center[(size_t)(g0+k)*3+2];
    }

    unsigned kl[4][4];
    #pragma unroll
    for (int k = 0; k < 4; ++k)
        #pragma unroll
        for (int q = 0; q < 4; ++q) kl[k][q] = 0xFFFFFFFFu;

    for (int half = 0; half < 2; ++half) {
        // ---- stage: 12288 dwords, stride-1 coalesced ----
        const float* src = bp + half * KNN_HALF_DW;
        #pragma unroll
        for (int i = 0; i < 48; ++i)
            sraw[i * 256 + t] = src[i * 256 + t];
        __syncthreads();

        // ---- hot loop: 64 pts/lane from LDS ----
        const unsigned gbase = (unsigned)(half * KNN_HALF_PTS);
        #pragma unroll 4
        for (int p = 0; p < 64; ++p) {
            int pi = p * 64 + lane;
            float x = sraw[pi*3 + 0];
            float y = sraw[pi*3 + 1];
            float z = sraw[pi*3 + 2];
            unsigned gi = gbase + (unsigned)pi;
            #pragma unroll
            for (int k = 0; k < 4; ++k) {
                float dx = x - cx[k], dy = y - cy[k], dz = z - cz[k];
                float d = dx*dx + dy*dy + dz*dz;     // contract OK (tolerance big)
                unsigned key = (__float_as_uint(d) & 0xFFFFE000u) | gi;
                unsigned m0 = kl[k][0] > key ? kl[k][0] : key;
                unsigned m1 = kl[k][1] > key ? kl[k][1] : key;
                unsigned m2 = kl[k][2] > key ? kl[k][2] : key;
                kl[k][0] = kl[k][0] < key ? kl[k][0] : key;
                kl[k][1] = kl[k][1] < m0  ? kl[k][1] : m0;
                kl[k][2] = kl[k][2] < m1  ? kl[k][2] : m1;
                kl[k][3] = kl[k][3] < m2  ? kl[k][3] : m2;
            }
        }
        __syncthreads();   // all waves done reading before restage
    }

    // ---- pop: 32 rounds, 4 groups interleaved (ILP) ----
    unsigned keepv[4] = {0u, 0u, 0u, 0u};
    #pragma unroll 1
    for (int r = 0; r < MSIZE; ++r) {
        unsigned kk[4];
        #pragma unroll
        for (int k = 0; k < 4; ++k) kk[k] = kl[k][0];
        #pragma unroll
        for (int k = 0; k < 4; ++k) kk[k] = dpp_min_u32_keep<0xB1>(kk[k]);
        #pragma unroll
        for (int k = 0; k < 4; ++k) kk[k] = dpp_min_u32_keep<0x4E>(kk[k]);
        #pragma unroll
        for (int k = 0; k < 4; ++k) kk[k] = dpp_min_u32_keep<0x141>(kk[k]);
        #pragma unroll
        for (int k = 0; k < 4; ++k) kk[k] = dpp_min_u32_keep<0x140>(kk[k]);
        #pragma unroll
        for (int k = 0; k < 4; ++k) kk[k] = dpp_min_u32_keep<0x142>(kk[k]);
        #pragma unroll
        for (int k = 0; k < 4; ++k) kk[k] = dpp_min_u32_keep<0x143>(kk[k]);
        #pragma unroll
        for (int k = 0; k < 4; ++k) {
            unsigned kmin = (unsigned)__builtin_amdgcn_readlane((int)kk[k], 63);
            if (lane == r) keepv[k] = kmin & 0x1FFFu;
            if (kl[k][0] == kmin) {
                kl[k][0] = kl[k][1]; kl[k][1] = kl[k][2]; kl[k][2] = kl[k][3];
                kl[k][3] = 0xFFFFFFFFu;
            }
        }
    }

    if (lane < MSIZE) {
        #pragma unroll
        for (int k = 0; k < 4; ++k) {
            int keep = (int)keepv[k];
            size_t o = (((size_t)(g0 + k)) * MSIZE + lane) * 3;
            float x = bp[keep*3+0], y = bp[keep*3+1], z = bp[keep*3+2];
            out_nbhd[o+0] = x - cx[k];
            out_nbhd[o+1] = y - cy[k];
            out_nbhd[o+2] = z - cz[k];
        }
    }
}

// ---------------------------------------------------------------------------
extern "C" void kernel_launch(void* const* d_in, const int* in_sizes, int n_in,
                              void* d_out, int out_size, void* d_ws, size_t ws_size,
                              hipStream_t stream)
{
    const float* xyz = (const float*)d_in[0];
    float* out        = (float*)d_out;
    float* out_nbhd   = out;                                    // 32*512*32*3
    float* out_center = out + (size_t)BATCH*NGROUP*MSIZE*3;     // 32*512*3
    float* out_fps    = out_center + (size_t)BATCH*NGROUP*3;    // 32*512

    hipFuncSetAttribute(reinterpret_cast<const void*>(fps_kernel),
                        hipFuncAttributeMaxDynamicSharedMemorySize,
                        DYN_LDS_BYTES);

    fps_kernel<<<dim3(BATCH), dim3(FPS_THREADS), DYN_LDS_BYTES, stream>>>(xyz, out_center, out_fps);
    knn_kernel<<<dim3(BATCH*NGROUP/16), dim3(256), KNN_LDS_BYTES, stream>>>(xyz, out_center, out_nbhd);
}